// Round 3
// baseline (2967.725 us; speedup 1.0000x reference)
//
#include <hip/hip_runtime.h>
#include <hip/hip_fp16.h>

typedef _Float16 half2_t __attribute__((ext_vector_type(2)));
typedef _Float16 half8_t __attribute__((ext_vector_type(8)));
typedef float f32x4 __attribute__((ext_vector_type(4)));

struct __align__(16) H2x4 { half2_t h[4]; };

__device__ __forceinline__ float fdot2f(half2_t a, half2_t b, float c){
#if __has_builtin(__builtin_amdgcn_fdot2)
  return __builtin_amdgcn_fdot2(a, b, c, false);
#else
  return c + (float)a[0]*(float)b[0] + (float)a[1]*(float)b[1];
#endif
}

__device__ __forceinline__ float fast_exp2f(float x){
#if __has_builtin(__builtin_amdgcn_exp2f)
  return __builtin_amdgcn_exp2f(x);
#else
  return __expf(x*0.6931471805599453f);
#endif
}

// ---------------- prep: fp32 -> f16 casts ----------------
struct PrepArgs {
  const float* src[13];
  __half* dst[13];
  int n[13];
};
__global__ __launch_bounds__(256) void prep_cast_k(PrepArgs a){
  const int r = blockIdx.y;
  const int n = a.n[r];
  const float* __restrict__ s = a.src[r];
  __half* __restrict__ d = a.dst[r];
  for (int i = blockIdx.x*256 + threadIdx.x; i < n; i += gridDim.x*256)
    d[i] = __float2half(s[i]);
}

struct BiasArgs {
  const float *bih0f,*bhh0f,*bih0b,*bhh0b,*bih1f,*bhh1f,*bih1b,*bhh1b;
  const float *b1t1,*b1t2,*b2t1,*b2t2;
  float *b0,*b1,*bz,*by;
};
__global__ __launch_bounds__(256) void prep_bias_k(BiasArgs a){
  const int i = threadIdx.x;
  if (i < 256){
    a.b0[i]     = a.bih0f[i] + a.bhh0f[i];
    a.b0[256+i] = a.bih0b[i] + a.bhh0b[i];
    a.b1[i]     = a.bih1f[i] + a.bhh1f[i];
    a.b1[256+i] = a.bih1b[i] + a.bhh1b[i];
  }
  if (i < 128){ a.bz[i] = a.b1t1[i]; a.bz[128+i] = a.b1t2[i]; }
  if (i < 32){  a.by[i] = a.b2t1[i]; a.by[32+i]  = a.b2t2[i]; }
}

// ---------------- GEMM: C[m][n] = sum_k A[m][k]*B[n][k] + bias[n] ----------------
// A: f16 [M][K] row-major; B: f16 [N][K] row-major (weight layout).
// Output f16 at C[(n>>8)*dirStride + m*256 + (n&255)]  (pre/z layouts).
template<bool RELU>
__global__ __launch_bounds__(256,2) void gemm_nt_k(
    const __half* __restrict__ A, const __half* __restrict__ B,
    __half* __restrict__ C, const float* __restrict__ bias,
    int M, int N, int K, long dirStride)
{
  __shared__ __align__(16) _Float16 As[128*40];
  __shared__ __align__(16) _Float16 Bs[128*40];
  const int tid = threadIdx.x;
  const int wave = tid>>6, lane = tid&63;
  const int wr = wave>>1, wc = wave&1;
  const int lrow = lane&15, lk = lane>>4;
  const int m0 = blockIdx.x*128, n0 = blockIdx.y*128;
  f32x4 acc[4][4];
  #pragma unroll
  for (int i=0;i<4;i++)
    #pragma unroll
    for (int j=0;j<4;j++) acc[i][j] = (f32x4){0.f,0.f,0.f,0.f};

  for (int k0=0; k0<K; k0+=32){
    __syncthreads();
    #pragma unroll
    for (int i=0;i<2;i++){
      int idx = i*256 + tid;
      int row = idx>>2, ch = idx&3;
      const int4 av = *(const int4*)(A + (size_t)(m0+row)*K + k0 + ch*8);
      const int4 bv = *(const int4*)(B + (size_t)(n0+row)*K + k0 + ch*8);
      *(int4*)(As + row*40 + ch*8) = av;
      *(int4*)(Bs + row*40 + ch*8) = bv;
    }
    __syncthreads();
    half8_t af[4], bf[4];
    #pragma unroll
    for (int mi=0;mi<4;mi++) af[mi] = *(const half8_t*)(As + (wr*64+mi*16+lrow)*40 + lk*8);
    #pragma unroll
    for (int ni=0;ni<4;ni++) bf[ni] = *(const half8_t*)(Bs + (wc*64+ni*16+lrow)*40 + lk*8);
    #pragma unroll
    for (int mi=0;mi<4;mi++)
      #pragma unroll
      for (int ni=0;ni<4;ni++)
        acc[mi][ni] = __builtin_amdgcn_mfma_f32_16x16x32_f16(af[mi], bf[ni], acc[mi][ni], 0,0,0);
  }
  #pragma unroll
  for (int mi=0;mi<4;mi++){
    #pragma unroll
    for (int ni=0;ni<4;ni++){
      const int n = n0 + wc*64 + ni*16 + lrow;
      const float bv = bias[n];
      const size_t base = (size_t)(n>>8)*dirStride + (size_t)(n&255);
      #pragma unroll
      for (int r2=0;r2<4;r2++){
        const int m = m0 + wr*64 + mi*16 + lk*4 + r2;
        float v = acc[mi][ni][r2] + bv;
        if (RELU) v = fmaxf(v, 0.f);
        C[(size_t)m*256 + base] = __float2half(v);
      }
    }
  }
}

// ---------------- recurrence: one (dir,batch) chain per workgroup ----------------
// pre: f16 [2][B*T][256] with m = batch*T + t ; whh: f16 [2][256][256]
// out: f16 [B*T][512], fwd at cols 0..255, bwd at 256..511
__global__ __launch_bounds__(256,1) void rnn_layer_k(
    const __half* __restrict__ pre, const __half* __restrict__ whh,
    __half* __restrict__ out, int T)
{
  const int dir = blockIdx.x >> 4;
  const int batch = blockIdx.x & 15;
  const int tid = threadIdx.x;
  half2_t w[128];
  {
    const int4* wp = (const int4*)(whh + dir*65536 + tid*256);
    #pragma unroll
    for (int c=0;c<32;c++){
      H2x4 q = __builtin_bit_cast(H2x4, wp[c]);
      w[4*c+0]=q.h[0]; w[4*c+1]=q.h[1]; w[4*c+2]=q.h[2]; w[4*c+3]=q.h[3];
    }
  }
  __shared__ __align__(16) half2_t hbuf[2][128];
  if (tid < 128){ half2_t z; z[0]=(_Float16)0.f; z[1]=(_Float16)0.f; hbuf[0][tid]=z; }
  const int ttstep = dir ? -256 : 256;
  const int ostep  = dir ? -512 : 512;
  const int t0 = dir ? (T-1) : 0;
  const __half* pcur = pre + (size_t)dir*8388608 + ((size_t)batch*T + t0)*256 + tid;
  __half* ocur = out + ((size_t)batch*T + t0)*512 + dir*256 + tid;
  float u_cur = __half2float(*pcur);
  __syncthreads();
  for (int t=0; t<T; ++t){
    if (t+1 < T) pcur += ttstep;
    const float u_next = __half2float(*pcur);   // prefetch next step's pre
    float a0=u_cur, a1=0.f, a2=0.f, a3=0.f;
    const H2x4* hb = (const H2x4*)hbuf[t&1];
    #pragma unroll
    for (int c=0;c<32;c++){
      H2x4 hv = hb[c];                           // 16B broadcast LDS read
      a0 = fdot2f(w[4*c+0], hv.h[0], a0);
      a1 = fdot2f(w[4*c+1], hv.h[1], a1);
      a2 = fdot2f(w[4*c+2], hv.h[2], a2);
      a3 = fdot2f(w[4*c+3], hv.h[3], a3);
    }
    const float x = (a0+a1)+(a2+a3);
    const float e2 = fast_exp2f(x * 2.8853900817779268f);      // e^{2x}
    const float h  = fmaf(-2.f, __builtin_amdgcn_rcpf(1.f + e2), 1.f); // tanh(x)
    *ocur = __float2half(h);
    ocur += ostep;
    const float ho = __shfl_xor(h, 1, 64);
    if (!(tid & 1)){
      half2_t hw; hw[0]=(_Float16)h; hw[1]=(_Float16)ho;
      hbuf[(t&1)^1][tid>>1] = hw;
    }
    u_cur = u_next;
    __syncthreads();
  }
}

// ---------------- heads stage-2: y = z @ W2^T + b2 -> d_out (fp32) ----------------
// z: f16 [32768][256] (head1 cols 0..127, head2 cols 128..255)
// w2: f16 [64][128] (W2t1 rows 0..31, W2t2 rows 32..63); out: y1 then y2, each [m][32]
__global__ __launch_bounds__(256,4) void head2_k(
    const __half* __restrict__ z, const __half* __restrict__ w2,
    const float* __restrict__ by, float* __restrict__ yout)
{
  __shared__ _Float16 w2s[64*130];
  __shared__ __align__(16) _Float16 zs[4*256];
  const int tid = threadIdx.x;
  {
    const half2_t* g = (const half2_t*)w2;
    for (int idx=tid; idx<4096; idx+=256){
      int row=idx>>6, c=idx&63;
      *(half2_t*)(w2s + row*130 + c*2) = g[idx];
    }
  }
  const int m0 = blockIdx.x*4;
  if (tid < 128){
    const int4* g = (const int4*)(z + (size_t)m0*256);
    *(int4*)(zs + (tid>>5)*256 + (tid&31)*8) = g[tid];
  }
  __syncthreads();
  const int r = tid>>6, n = tid&63;
  const int head = n>>5;
  const half2_t* zp = (const half2_t*)(zs + r*256) + head*64;
  const half2_t* wp = (const half2_t*)(w2s + n*130);
  float acc0=by[n], acc1=0.f;
  #pragma unroll
  for (int j=0;j<64;j+=2){
    acc0 = fdot2f(zp[j],   wp[j],   acc0);
    acc1 = fdot2f(zp[j+1], wp[j+1], acc1);
  }
  yout[(size_t)head*1048576 + (size_t)(m0+r)*32 + (n&31)] = acc0+acc1;
}

extern "C" void kernel_launch(void* const* d_in, const int* in_sizes, int n_in,
                              void* d_out, int out_size, void* d_ws, size_t ws_size,
                              hipStream_t stream)
{
  (void)in_sizes; (void)n_in; (void)out_size; (void)ws_size;
  const float* X    =(const float*)d_in[0];
  const float* Wih0f=(const float*)d_in[1];
  const float* Whh0f=(const float*)d_in[2];
  const float* bih0f=(const float*)d_in[3];
  const float* bhh0f=(const float*)d_in[4];
  const float* Wih0b=(const float*)d_in[5];
  const float* Whh0b=(const float*)d_in[6];
  const float* bih0b=(const float*)d_in[7];
  const float* bhh0b=(const float*)d_in[8];
  const float* Wih1f=(const float*)d_in[9];
  const float* Whh1f=(const float*)d_in[10];
  const float* bih1f=(const float*)d_in[11];
  const float* bhh1f=(const float*)d_in[12];
  const float* Wih1b=(const float*)d_in[13];
  const float* Whh1b=(const float*)d_in[14];
  const float* bih1b=(const float*)d_in[15];
  const float* bhh1b=(const float*)d_in[16];
  const float* W1t1 =(const float*)d_in[17];
  const float* b1t1 =(const float*)d_in[18];
  const float* W2t1 =(const float*)d_in[19];
  const float* b2t1 =(const float*)d_in[20];
  const float* W1t2 =(const float*)d_in[21];
  const float* b1t2 =(const float*)d_in[22];
  const float* W2t2 =(const float*)d_in[23];
  const float* b2t2 =(const float*)d_in[24];

  char* ws = (char*)d_ws;
  size_t off = 0;
  auto alloc = [&](size_t bytes)->void*{ void* p = ws + off; off += (bytes + 1023) & ~(size_t)1023; return p; };
  __half* x16  = (__half*)alloc((size_t)4194304*2);
  __half* wih0 = (__half*)alloc((size_t)65536*2);
  __half* whh0 = (__half*)alloc((size_t)131072*2);
  __half* wih1 = (__half*)alloc((size_t)262144*2);
  __half* whh1 = (__half*)alloc((size_t)131072*2);
  __half* w1   = (__half*)alloc((size_t)131072*2);
  __half* w2   = (__half*)alloc((size_t)8192*2);
  float* b0 = (float*)alloc(512*4);
  float* b1 = (float*)alloc(512*4);
  float* bz = (float*)alloc(256*4);
  float* by = (float*)alloc(64*4);
  __half* preP = (__half*)alloc((size_t)16777216*2); // shared: pre0 / pre1 / z
  __half* out0 = (__half*)alloc((size_t)16777216*2);
  __half* out1 = (__half*)alloc((size_t)16777216*2);

  PrepArgs pa;
  auto set=[&](int r, const float* s, __half* d, int n){ pa.src[r]=s; pa.dst[r]=d; pa.n[r]=n; };
  set(0, X, x16, 4194304);
  set(1, Wih0f, wih0, 32768);       set(2, Wih0b, wih0+32768, 32768);
  set(3, Whh0f, whh0, 65536);       set(4, Whh0b, whh0+65536, 65536);
  set(5, Wih1f, wih1, 131072);      set(6, Wih1b, wih1+131072, 131072);
  set(7, Whh1f, whh1, 65536);       set(8, Whh1b, whh1+65536, 65536);
  set(9, W1t1, w1, 65536);          set(10, W1t2, w1+65536, 65536);
  set(11, W2t1, w2, 4096);          set(12, W2t2, w2+4096, 4096);
  prep_cast_k<<<dim3(1024,13),256,0,stream>>>(pa);

  BiasArgs ba = {bih0f,bhh0f,bih0b,bhh0b,bih1f,bhh1f,bih1b,bhh1b,b1t1,b1t2,b2t1,b2t2,b0,b1,bz,by};
  prep_bias_k<<<1,256,0,stream>>>(ba);

  // layer 0
  gemm_nt_k<false><<<dim3(256,4),256,0,stream>>>(x16, wih0, preP, b0, 32768,512,128, 8388608L);
  rnn_layer_k<<<32,256,0,stream>>>(preP, whh0, out0, 2048);
  // layer 1
  gemm_nt_k<false><<<dim3(256,4),256,0,stream>>>(out0, wih1, preP, b1, 32768,512,512, 8388608L);
  rnn_layer_k<<<32,256,0,stream>>>(preP, whh1, out1, 2048);
  // heads
  gemm_nt_k<true><<<dim3(256,2),256,0,stream>>>(out1, w1, preP, bz, 32768,256,512, 0L);
  head2_k<<<8192,256,0,stream>>>(preP, w2, by, (float*)d_out);
}